// Round 3
// baseline (5872.577 us; speedup 1.0000x reference)
//
#include <hip/hip_runtime.h>
#include <cstdint>

// ---------------------------------------------------------------------------
// GCN Siamese, bucketed-bin + LDS-accumulate formulation, bf16 gather tables.
//   per branch:
//     k_bcnt: count edges per (dst>>6 bucket, blockIdx%8 class)   [XCD-local]
//     k_bscan: exclusive scan -> claim counters + bucket starts
//     k_bin: claim + write packed (src<<6)|(dst&63)  (writes ~13MB, L2-local)
//     k_dinv: per-bucket LDS histogram -> dinv = rsqrt(deg+1)
//     k_mm<128>: XWs = bf16(dinv * (X@W1))
//     k_agg<false>: per-bucket 64x64 LDS tile, gather XWs rows, ds_add;
//                   epilogue H1 = bf16(relu(di*(acc+XWs[i]) + b1))
//     k_mm<64>:  XWs2 = bf16(dinv * (H1@W2))
//     k_agg<true>: same, epilogue pools into emb/cnt (global atomics)
//   head: sigmoid(relu([e1,e2,|e1-e2|]@fc1+b)@fc2+b)
// ---------------------------------------------------------------------------

#define NBSHIFT 6          // 64 dst nodes per bucket

__device__ __forceinline__ float fatomic(float* p, float v) {
    return unsafeAtomicAdd(p, v);   // hw global_atomic_add_f32
}
__device__ __forceinline__ float bf2f(unsigned short u) {
    union { unsigned int i; float f; } c; c.i = ((unsigned int)u) << 16; return c.f;
}
__device__ __forceinline__ unsigned short f2bf(float f) {
    union { float f; unsigned int i; } c; c.f = f;
    const unsigned int b = c.i;
    return (unsigned short)((b + 0x7FFF + ((b >> 16) & 1)) >> 16);   // RNE
}

// count per (bucket, class) ; class = blockIdx%8 (XCD round-robin)
__global__ void k_bcnt(const int* __restrict__ dst, int* __restrict__ bcnt, int E) {
    int i = blockIdx.x * blockDim.x + threadIdx.x;
    const int cls = blockIdx.x & 7;
    const int stride = gridDim.x * blockDim.x;
    for (; i < E; i += stride)
        atomicAdd(&bcnt[(dst[i] >> NBSHIFT) * 8 + cls], 1);
}

// exclusive scan over NB8 = NB*8 entries (b-major, class-minor).
// cur[i] = claim base; bstart[b] = bucket b's list start; bstart[NB] = E.
__global__ __launch_bounds__(1024) void k_bscan(const int* __restrict__ bcnt,
                                                int* __restrict__ cur,
                                                int* __restrict__ bstart,
                                                int NB8, int E) {
    __shared__ int sm[1024];
    const int t = threadIdx.x;
    const int per = (NB8 + 1023) / 1024;
    const int s = t * per, e = min(s + per, NB8);
    int sum = 0;
    for (int i = s; i < e; ++i) sum += bcnt[i];
    sm[t] = sum;
    __syncthreads();
    for (int off = 1; off < 1024; off <<= 1) {
        const int u = (t >= off) ? sm[t - off] : 0;
        __syncthreads();
        sm[t] += u;
        __syncthreads();
    }
    int run = sm[t] - sum;            // exclusive prefix of this chunk
    for (int i = s; i < e; ++i) {
        cur[i] = run;
        if ((i & 7) == 0) bstart[i >> 3] = run;
        run += bcnt[i];
    }
    if (t == 0) bstart[NB8 >> 3] = E;
}

// claim + write packed word. Same grid/mapping as k_bcnt -> exact capacity.
__global__ void k_bin(const int* __restrict__ src, const int* __restrict__ dst,
                      int* __restrict__ cur, int* __restrict__ col, int E) {
    int i = blockIdx.x * blockDim.x + threadIdx.x;
    const int cls = blockIdx.x & 7;
    const int stride = gridDim.x * blockDim.x;
    for (; i < E; i += stride) {
        const int d = dst[i];
        const int pos = atomicAdd(&cur[(d >> NBSHIFT) * 8 + cls], 1);
        col[pos] = (src[i] << NBSHIFT) | (d & 63);
    }
}

// per-bucket degree histogram -> dinv
__global__ __launch_bounds__(256) void k_dinv(const int* __restrict__ col,
                                              const int* __restrict__ bstart,
                                              float* __restrict__ dinv, int N) {
    __shared__ int c[64];
    const int t = threadIdx.x;
    const int b = blockIdx.x;
    if (t < 64) c[t] = 0;
    __syncthreads();
    const int s = bstart[b], e = bstart[b + 1];
    for (int i = s + t; i < e; i += 256) atomicAdd(&c[col[i] & 63], 1);
    __syncthreads();
    if (t < 64) {
        const int ni = (b << NBSHIFT) + t;
        if (ni < N) dinv[ni] = rsqrtf((float)c[t] + 1.0f);
    }
}

// Y[row] = bf16(dinv[row] * (X@W)[row]) ; X is f32 or bf16
template <int K, bool BF16IN>
__global__ __launch_bounds__(256) void k_mm(const void* __restrict__ Xv,
                                            const float* __restrict__ W,
                                            const float* __restrict__ dinv,
                                            unsigned short* __restrict__ Y, int n) {
    __shared__ float WL[K * 64];
    __shared__ float XT[32 * K];
    const int tid = threadIdx.x;
    for (int i = tid * 4; i < K * 64; i += 1024)
        *(float4*)&WL[i] = *(const float4*)&W[i];
    const int rowBase = blockIdx.x * 32;
    const int rows = min(32, n - rowBase);
    if (BF16IN) {
        const unsigned short* xs = (const unsigned short*)Xv + (size_t)rowBase * K;
        for (int i = tid * 4; i < rows * K; i += 1024) {
            const ushort4 u = *(const ushort4*)&xs[i];
            XT[i + 0] = bf2f(u.x); XT[i + 1] = bf2f(u.y);
            XT[i + 2] = bf2f(u.z); XT[i + 3] = bf2f(u.w);
        }
    } else {
        const float* xs = (const float*)Xv + (size_t)rowBase * K;
        for (int i = tid * 4; i < rows * K; i += 1024)
            *(float4*)&XT[i] = *(const float4*)&xs[i];
    }
    __syncthreads();
    const int colf = tid & 63;
    const int rg = tid >> 6;
    float acc[8] = {};
    for (int k4 = 0; k4 < K / 4; ++k4) {
        const float w0 = WL[(k4 * 4 + 0) * 64 + colf];
        const float w1 = WL[(k4 * 4 + 1) * 64 + colf];
        const float w2 = WL[(k4 * 4 + 2) * 64 + colf];
        const float w3 = WL[(k4 * 4 + 3) * 64 + colf];
#pragma unroll
        for (int r = 0; r < 8; ++r) {
            const float4 xv = *(const float4*)&XT[(rg * 8 + r) * K + k4 * 4];
            acc[r] += xv.x * w0 + xv.y * w1 + xv.z * w2 + xv.w * w3;
        }
    }
#pragma unroll
    for (int r = 0; r < 8; ++r) {
        const int row = rowBase + rg * 8 + r;
        if (row < n) Y[(size_t)row * 64 + colf] = f2bf(dinv[row] * acc[r]);
    }
}

// per-bucket gather-aggregate into 64x64 LDS tile.
template <bool POOL>
__global__ __launch_bounds__(256) void k_agg(const int* __restrict__ col,
                                             const int* __restrict__ bstart,
                                             const float* __restrict__ dinv,
                                             const unsigned short* __restrict__ XWs,
                                             const float* __restrict__ bias,
                                             unsigned short* __restrict__ Hout,
                                             const int* __restrict__ batch,
                                             float* __restrict__ emb,
                                             float* __restrict__ cnt, int N) {
    __shared__ float acc[64 * 64];
    const int tid = threadIdx.x;
    const int lane = tid & 63;
    const int wv = tid >> 6;
    const int b = blockIdx.x;
    for (int i = tid; i < 64 * 64; i += 256) acc[i] = 0.0f;
    __syncthreads();
    const int s = bstart[b], e = bstart[b + 1];
    for (int base = s + (wv << 6); base < e; base += 256) {
        const int m = min(64, e - base);
        int pk = 0;
        if (lane < m) pk = col[base + lane];      // 1 coalesced load / 64 edges
#pragma unroll 4
        for (int j = 0; j < m; ++j) {
            const int v = __shfl(pk, j);
            const float f = bf2f(XWs[(size_t)(v >> NBSHIFT) * 64 + lane]);
            atomicAdd(&acc[((v & 63) << 6) + lane], f);
        }
    }
    __syncthreads();
    const float bl = bias[lane];
    for (int nd = wv; nd < 64; nd += 4) {
        const int ni = (b << NBSHIFT) + nd;
        if (ni >= N) break;
        const float di = dinv[ni];
        const float self = bf2f(XWs[(size_t)ni * 64 + lane]);
        const float v = fmaxf(di * (acc[(nd << 6) + lane] + self) + bl, 0.0f);
        if (POOL) {
            const int g = batch[ni];
            fatomic(&emb[(size_t)g * 64 + lane], v);
            if (lane == 0) fatomic(&cnt[g], 1.0f);
        } else {
            Hout[(size_t)ni * 64 + lane] = f2bf(v);
        }
    }
}

// head: emb -> [e1,e2,|e1-e2|] @ fc1 -> relu -> @ fc2 -> sigmoid
__global__ __launch_bounds__(64) void k_head(const float* __restrict__ emb1, const float* __restrict__ cnt1,
                                             const float* __restrict__ emb2, const float* __restrict__ cnt2,
                                             const float* __restrict__ fc1W, const float* __restrict__ fc1b,
                                             const float* __restrict__ fc2W, const float* __restrict__ fc2b,
                                             float* __restrict__ out) {
    const int g = blockIdx.x;
    const int lane = threadIdx.x;
    __shared__ float comb[192];
    const float c1 = fmaxf(cnt1[g], 1.0f), c2 = fmaxf(cnt2[g], 1.0f);
    const float e1 = emb1[g * 64 + lane] / c1;
    const float e2 = emb2[g * 64 + lane] / c2;
    comb[lane] = e1;
    comb[64 + lane] = e2;
    comb[128 + lane] = fabsf(e1 - e2);
    __syncthreads();
    float acc = fc1b[lane];
    for (int k = 0; k < 192; ++k) acc += comb[k] * fc1W[k * 64 + lane];
    const float o1 = fmaxf(acc, 0.0f);
    float p = o1 * fc2W[lane];
#pragma unroll
    for (int off = 32; off > 0; off >>= 1) p += __shfl_xor(p, off);
    if (lane == 0) out[g] = 1.0f / (1.0f + expf(-(p + fc2b[0])));
}

extern "C" void kernel_launch(void* const* d_in, const int* in_sizes, int n_in,
                              void* d_out, int out_size, void* d_ws, size_t ws_size,
                              hipStream_t stream) {
    const float* x1   = (const float*)d_in[0];
    const int*   ei1  = (const int*)d_in[1];
    const int*   bt1  = (const int*)d_in[2];
    const float* x2   = (const float*)d_in[3];
    const int*   ei2  = (const int*)d_in[4];
    const int*   bt2  = (const int*)d_in[5];
    const float* W1   = (const float*)d_in[6];
    const float* bb1  = (const float*)d_in[7];
    const float* W2   = (const float*)d_in[8];
    const float* bb2  = (const float*)d_in[9];
    const float* fc1W = (const float*)d_in[10];
    const float* fc1b = (const float*)d_in[11];
    const float* fc2W = (const float*)d_in[12];
    const float* fc2b = (const float*)d_in[13];
    float* out = (float*)d_out;

    const int N = in_sizes[0] / 128;
    const int E = in_sizes[1] / 2;
    const int G = out_size;
    const int NB = (N + 63) >> NBSHIFT;
    const int NB8 = NB * 8;

    // workspace layout (f32/int first, then bf16 tables)
    float* dinv  = (float*)d_ws;                     // N
    float* emb1  = dinv + N;                         // G*64
    float* cnt1  = emb1 + (size_t)G * 64;            // G
    float* emb2  = cnt1 + G;                         // G*64
    float* cnt2  = emb2 + (size_t)G * 64;            // G
    int*   bcnt  = (int*)(cnt2 + G);                 // NB8
    int*   cur   = bcnt + NB8;                       // NB8
    int*   bstart= cur + NB8;                        // NB+1
    int*   col   = bstart + (NB + 1);                // E
    unsigned short* XWs = (unsigned short*)(col + E);        // N*64
    unsigned short* H1  = XWs + (size_t)N * 64;              // N*64

    const int mmGrid = (N + 31) / 32;

    for (int br = 0; br < 2; ++br) {
        const float* X = br ? x2 : x1;
        const int* ei  = br ? ei2 : ei1;
        const int* bt  = br ? bt2 : bt1;
        float* emb = br ? emb2 : emb1;
        float* cnt = br ? cnt2 : cnt1;
        const int* srcp = ei;
        const int* dstp = ei + E;

        hipMemsetAsync(bcnt, 0, (size_t)NB8 * 4, stream);
        k_bcnt<<<2048, 256, 0, stream>>>(dstp, bcnt, E);
        k_bscan<<<1, 1024, 0, stream>>>(bcnt, cur, bstart, NB8, E);
        k_bin<<<2048, 256, 0, stream>>>(srcp, dstp, cur, col, E);
        k_dinv<<<NB, 256, 0, stream>>>(col, bstart, dinv, N);

        k_mm<128, false><<<mmGrid, 256, 0, stream>>>(X, W1, dinv, XWs, N);
        k_agg<false><<<NB, 256, 0, stream>>>(col, bstart, dinv, XWs, bb1,
                                             H1, nullptr, nullptr, nullptr, N);
        k_mm<64, true><<<mmGrid, 256, 0, stream>>>(H1, W2, dinv, XWs, N);
        hipMemsetAsync(emb, 0, (size_t)(G * 64 + G) * 4, stream);
        k_agg<true><<<NB, 256, 0, stream>>>(col, bstart, dinv, XWs, bb2,
                                            nullptr, bt, emb, cnt, N);
    }
    k_head<<<G, 64, 0, stream>>>(emb1, cnt1, emb2, cnt2, fc1W, fc1b, fc2W, fc2b, out);
}

// Round 4
// 2940.172 us; speedup vs baseline: 1.9974x; 1.9974x over previous
//
#include <hip/hip_runtime.h>
#include <cstdint>

// ---------------------------------------------------------------------------
// GCN Siamese. Node-major binning -> per-node CSR -> per-node-wave gather agg.
//   per branch:
//     k_bcnt : count per (dst node, blockIdx%8 class)      [800K int counters]
//     k_bscan: exclusive scan -> cur (claim bases), rowstart[N+1], dinv
//     k_bin  : claim + write col[pos]=src (node-major order, XCD-local frontiers)
//     k_mm<128>: XWs = bf16(dinv * (X@W1))
//     k_agg<false>: wave per node, unroll-8 gather of bf16 rows;
//                   H1 = bf16(relu(di*(acc+XWs[i]) + b1))
//     k_mm<64> : XWs2 = bf16(dinv * (H1@W2))
//     k_agg<true>: same gather, epilogue pools into emb/cnt (global atomics)
//   head: sigmoid(relu([e1,e2,|e1-e2|]@fc1+b)@fc2+b)
// N=100000, E=3.2M, G=1024
// ---------------------------------------------------------------------------

__device__ __forceinline__ float fatomic(float* p, float v) {
    return unsafeAtomicAdd(p, v);   // hw global_atomic_add_f32
}
__device__ __forceinline__ float bf2f(unsigned short u) {
    union { unsigned int i; float f; } c; c.i = ((unsigned int)u) << 16; return c.f;
}
__device__ __forceinline__ unsigned short f2bf(float f) {
    union { float f; unsigned int i; } c; c.f = f;
    const unsigned int b = c.i;
    return (unsigned short)((b + 0x7FFF + ((b >> 16) & 1)) >> 16);   // RNE
}

// count per (dst node, class); class = blockIdx%8 (XCD round-robin)
__global__ void k_bcnt(const int* __restrict__ dst, int* __restrict__ bcnt, int E) {
    int i = blockIdx.x * blockDim.x + threadIdx.x;
    const int cls = blockIdx.x & 7;
    const int stride = gridDim.x * blockDim.x;
    for (; i < E; i += stride)
        atomicAdd(&bcnt[(dst[i] << 3) + cls], 1);
}

// exclusive scan over Nn*8 (node-major, class-minor) -> cur, rowstart, dinv
__global__ __launch_bounds__(1024) void k_bscan(const int* __restrict__ bcnt,
                                                int* __restrict__ cur,
                                                int* __restrict__ rowstart,
                                                float* __restrict__ dinv,
                                                int Nn, int E) {
    __shared__ int sm[1024];
    const int t = threadIdx.x;
    const int NB8 = Nn << 3;
    const int per = (((NB8 + 1023) >> 10) + 7) & ~7;   // multiple of 8 -> node-aligned
    const int s = t * per, e = min(s + per, NB8);
    int sum = 0;
    for (int i = s; i < e; ++i) sum += bcnt[i];
    sm[t] = sum;
    __syncthreads();
    for (int off = 1; off < 1024; off <<= 1) {
        const int u = (t >= off) ? sm[t - off] : 0;
        __syncthreads();
        sm[t] += u;
        __syncthreads();
    }
    int run = sm[t] - sum;            // exclusive prefix of this chunk
    for (int i = s; i < e; i += 8) {
        const int node = i >> 3;
        rowstart[node] = run;
        int deg = 0;
#pragma unroll
        for (int c = 0; c < 8; ++c) {
            const int v = bcnt[i + c];
            cur[i + c] = run;
            run += v; deg += v;
        }
        dinv[node] = rsqrtf((float)deg + 1.0f);
    }
    if (t == 0) rowstart[Nn] = E;
}

// claim + write col[pos] = src. Same grid/mapping as k_bcnt -> exact capacity.
__global__ void k_bin(const int* __restrict__ src, const int* __restrict__ dst,
                      int* __restrict__ cur, int* __restrict__ col, int E) {
    int i = blockIdx.x * blockDim.x + threadIdx.x;
    const int cls = blockIdx.x & 7;
    const int stride = gridDim.x * blockDim.x;
    for (; i < E; i += stride) {
        const int pos = atomicAdd(&cur[(dst[i] << 3) + cls], 1);
        col[pos] = src[i];
    }
}

// Y[row] = bf16(dinv[row] * (X@W)[row]) ; X is f32 or bf16
template <int K, bool BF16IN>
__global__ __launch_bounds__(256) void k_mm(const void* __restrict__ Xv,
                                            const float* __restrict__ W,
                                            const float* __restrict__ dinv,
                                            unsigned short* __restrict__ Y, int n) {
    __shared__ float WL[K * 64];
    __shared__ float XT[32 * K];
    const int tid = threadIdx.x;
    for (int i = tid * 4; i < K * 64; i += 1024)
        *(float4*)&WL[i] = *(const float4*)&W[i];
    const int rowBase = blockIdx.x * 32;
    const int rows = min(32, n - rowBase);
    if (BF16IN) {
        const unsigned short* xs = (const unsigned short*)Xv + (size_t)rowBase * K;
        for (int i = tid * 4; i < rows * K; i += 1024) {
            const ushort4 u = *(const ushort4*)&xs[i];
            XT[i + 0] = bf2f(u.x); XT[i + 1] = bf2f(u.y);
            XT[i + 2] = bf2f(u.z); XT[i + 3] = bf2f(u.w);
        }
    } else {
        const float* xs = (const float*)Xv + (size_t)rowBase * K;
        for (int i = tid * 4; i < rows * K; i += 1024)
            *(float4*)&XT[i] = *(const float4*)&xs[i];
    }
    __syncthreads();
    const int colf = tid & 63;
    const int rg = tid >> 6;
    float acc[8] = {};
    for (int k4 = 0; k4 < K / 4; ++k4) {
        const float w0 = WL[(k4 * 4 + 0) * 64 + colf];
        const float w1 = WL[(k4 * 4 + 1) * 64 + colf];
        const float w2 = WL[(k4 * 4 + 2) * 64 + colf];
        const float w3 = WL[(k4 * 4 + 3) * 64 + colf];
#pragma unroll
        for (int r = 0; r < 8; ++r) {
            const float4 xv = *(const float4*)&XT[(rg * 8 + r) * K + k4 * 4];
            acc[r] += xv.x * w0 + xv.y * w1 + xv.z * w2 + xv.w * w3;
        }
    }
#pragma unroll
    for (int r = 0; r < 8; ++r) {
        const int row = rowBase + rg * 8 + r;
        if (row < n) Y[(size_t)row * 64 + colf] = f2bf(dinv[row] * acc[r]);
    }
}

// CSR aggregation, one wave per dst node, lane = feature, unroll-8 gathers.
template <bool POOL>
__global__ __launch_bounds__(256) void k_agg(const int* __restrict__ col,
                                             const int* __restrict__ rowstart,
                                             const float* __restrict__ dinv,
                                             const unsigned short* __restrict__ XWs,
                                             const float* __restrict__ bias,
                                             unsigned short* __restrict__ Hout,
                                             const int* __restrict__ batch,
                                             float* __restrict__ emb,
                                             float* __restrict__ cnt, int Nn) {
    const int lane = threadIdx.x & 63;
    const int wid = (blockIdx.x * blockDim.x + threadIdx.x) >> 6;
    const int nw = (gridDim.x * blockDim.x) >> 6;
    const float bl = bias[lane];
    for (int i = wid; i < Nn; i += nw) {
        const int s = rowstart[i], e = rowstart[i + 1];
        float acc = 0.0f;
        int j = s;
        for (; j + 8 <= e; j += 8) {
            const int c0 = col[j + 0], c1 = col[j + 1], c2 = col[j + 2], c3 = col[j + 3];
            const int c4 = col[j + 4], c5 = col[j + 5], c6 = col[j + 6], c7 = col[j + 7];
            const float a0 = bf2f(XWs[(size_t)c0 * 64 + lane]);
            const float a1 = bf2f(XWs[(size_t)c1 * 64 + lane]);
            const float a2 = bf2f(XWs[(size_t)c2 * 64 + lane]);
            const float a3 = bf2f(XWs[(size_t)c3 * 64 + lane]);
            const float a4 = bf2f(XWs[(size_t)c4 * 64 + lane]);
            const float a5 = bf2f(XWs[(size_t)c5 * 64 + lane]);
            const float a6 = bf2f(XWs[(size_t)c6 * 64 + lane]);
            const float a7 = bf2f(XWs[(size_t)c7 * 64 + lane]);
            acc += ((a0 + a1) + (a2 + a3)) + ((a4 + a5) + (a6 + a7));
        }
        for (; j < e; ++j)
            acc += bf2f(XWs[(size_t)col[j] * 64 + lane]);
        const float di = dinv[i];
        const float self = bf2f(XWs[(size_t)i * 64 + lane]);
        const float v = fmaxf(di * (acc + self) + bl, 0.0f);
        if (POOL) {
            const int g = batch[i];
            fatomic(&emb[(size_t)g * 64 + lane], v);
            if (lane == 0) fatomic(&cnt[g], 1.0f);
        } else {
            Hout[(size_t)i * 64 + lane] = f2bf(v);
        }
    }
}

// head: emb -> [e1,e2,|e1-e2|] @ fc1 -> relu -> @ fc2 -> sigmoid
__global__ __launch_bounds__(64) void k_head(const float* __restrict__ emb1, const float* __restrict__ cnt1,
                                             const float* __restrict__ emb2, const float* __restrict__ cnt2,
                                             const float* __restrict__ fc1W, const float* __restrict__ fc1b,
                                             const float* __restrict__ fc2W, const float* __restrict__ fc2b,
                                             float* __restrict__ out) {
    const int g = blockIdx.x;
    const int lane = threadIdx.x;
    __shared__ float comb[192];
    const float c1 = fmaxf(cnt1[g], 1.0f), c2 = fmaxf(cnt2[g], 1.0f);
    const float e1 = emb1[g * 64 + lane] / c1;
    const float e2 = emb2[g * 64 + lane] / c2;
    comb[lane] = e1;
    comb[64 + lane] = e2;
    comb[128 + lane] = fabsf(e1 - e2);
    __syncthreads();
    float acc = fc1b[lane];
    for (int k = 0; k < 192; ++k) acc += comb[k] * fc1W[k * 64 + lane];
    const float o1 = fmaxf(acc, 0.0f);
    float p = o1 * fc2W[lane];
#pragma unroll
    for (int off = 32; off > 0; off >>= 1) p += __shfl_xor(p, off);
    if (lane == 0) out[g] = 1.0f / (1.0f + expf(-(p + fc2b[0])));
}

extern "C" void kernel_launch(void* const* d_in, const int* in_sizes, int n_in,
                              void* d_out, int out_size, void* d_ws, size_t ws_size,
                              hipStream_t stream) {
    const float* x1   = (const float*)d_in[0];
    const int*   ei1  = (const int*)d_in[1];
    const int*   bt1  = (const int*)d_in[2];
    const float* x2   = (const float*)d_in[3];
    const int*   ei2  = (const int*)d_in[4];
    const int*   bt2  = (const int*)d_in[5];
    const float* W1   = (const float*)d_in[6];
    const float* bb1  = (const float*)d_in[7];
    const float* W2   = (const float*)d_in[8];
    const float* bb2  = (const float*)d_in[9];
    const float* fc1W = (const float*)d_in[10];
    const float* fc1b = (const float*)d_in[11];
    const float* fc2W = (const float*)d_in[12];
    const float* fc2b = (const float*)d_in[13];
    float* out = (float*)d_out;

    const int N = in_sizes[0] / 128;
    const int E = in_sizes[1] / 2;
    const int G = out_size;

    float* dinv   = (float*)d_ws;                    // N
    float* emb1   = dinv + N;                        // G*64
    float* cnt1   = emb1 + (size_t)G * 64;           // G
    float* emb2   = cnt1 + G;                        // G*64
    float* cnt2   = emb2 + (size_t)G * 64;           // G
    int* rowstart = (int*)(cnt2 + G);                // N+1
    int* bcnt     = rowstart + (N + 1);              // N*8
    int* cur      = bcnt + (size_t)N * 8;            // N*8
    int* col      = cur + (size_t)N * 8;             // E
    unsigned short* XWs = (unsigned short*)(col + E);      // N*64
    unsigned short* H1  = XWs + (size_t)N * 64;            // N*64

    const int mmGrid = (N + 31) / 32;

    for (int br = 0; br < 2; ++br) {
        const float* X = br ? x2 : x1;
        const int* ei  = br ? ei2 : ei1;
        const int* bt  = br ? bt2 : bt1;
        float* emb = br ? emb2 : emb1;
        float* cnt = br ? cnt2 : cnt1;
        const int* srcp = ei;
        const int* dstp = ei + E;

        hipMemsetAsync(bcnt, 0, (size_t)N * 8 * 4, stream);
        k_bcnt<<<2048, 256, 0, stream>>>(dstp, bcnt, E);
        k_bscan<<<1, 1024, 0, stream>>>(bcnt, cur, rowstart, dinv, N, E);
        k_bin<<<2048, 256, 0, stream>>>(srcp, dstp, cur, col, E);

        k_mm<128, false><<<mmGrid, 256, 0, stream>>>(X, W1, dinv, XWs, N);
        k_agg<false><<<2048, 256, 0, stream>>>(col, rowstart, dinv, XWs, bb1,
                                               H1, nullptr, nullptr, nullptr, N);
        k_mm<64, true><<<mmGrid, 256, 0, stream>>>(H1, W2, dinv, XWs, N);
        hipMemsetAsync(emb, 0, (size_t)(G * 64 + G) * 4, stream);
        k_agg<true><<<2048, 256, 0, stream>>>(col, rowstart, dinv, XWs, bb2,
                                              nullptr, bt, emb, cnt, N);
    }
    k_head<<<G, 64, 0, stream>>>(emb1, cnt1, emb2, cnt2, fc1W, fc1b, fc2W, fc2b, out);
}

// Round 5
// 1650.190 us; speedup vs baseline: 3.5587x; 1.7817x over previous
//
#include <hip/hip_runtime.h>
#include <cstdint>

// ---------------------------------------------------------------------------
// GCN Siamese. Node-major binning -> per-node CSR -> per-node-wave gather agg.
//   per branch:
//     k_bcnt : count per (dst node, blockIdx%8 class)      [800K int counters]
//     k_scanA/B/C: hierarchical scan -> cur (claim bases), rowstart, dinv
//     k_bin  : claim + write col[pos]=src (node-major order, XCD-local frontiers)
//     k_mm<128>: XWs = bf16(dinv * (X@W1))
//     k_agg<false>: wave per node, unroll-8 gather of bf16 rows;
//                   H1 = bf16(relu(di*(acc+XWs[i]) + b1))
//     k_mm<64> : XWs2 = bf16(dinv * (H1@W2))
//     k_agg<true>: same gather, epilogue pools into emb/cnt (global atomics)
//   head: sigmoid(relu([e1,e2,|e1-e2|]@fc1+b)@fc2+b)
// N=100000, E=3.2M, G=1024
// ---------------------------------------------------------------------------

__device__ __forceinline__ float fatomic(float* p, float v) {
    return unsafeAtomicAdd(p, v);   // hw global_atomic_add_f32
}
__device__ __forceinline__ float bf2f(unsigned short u) {
    union { unsigned int i; float f; } c; c.i = ((unsigned int)u) << 16; return c.f;
}
__device__ __forceinline__ unsigned short f2bf(float f) {
    union { float f; unsigned int i; } c; c.f = f;
    const unsigned int b = c.i;
    return (unsigned short)((b + 0x7FFF + ((b >> 16) & 1)) >> 16);   // RNE
}

// count per (dst node, class); class = blockIdx%8 (XCD round-robin)
__global__ void k_bcnt(const int* __restrict__ dst, int* __restrict__ bcnt, int E) {
    int i = blockIdx.x * blockDim.x + threadIdx.x;
    const int cls = blockIdx.x & 7;
    const int stride = gridDim.x * blockDim.x;
    for (; i < E; i += stride)
        atomicAdd(&bcnt[(dst[i] << 3) + cls], 1);
}

// ---- hierarchical scan (3 phases, node-granular) --------------------------
// A: per-node degree (8 counters, two int4 loads) -> degN, dinv, block partial
__global__ __launch_bounds__(256) void k_scanA(const int* __restrict__ bcnt,
                                               int* __restrict__ degN,
                                               float* __restrict__ dinv,
                                               int* __restrict__ partial,
                                               int N, int npb) {
    __shared__ int sm[256];
    const int t = threadIdx.x;
    const int n0 = blockIdx.x * npb;
    const int n1 = min(n0 + npb, N);
    int sum = 0;
    for (int nd = n0 + t; nd < n1; nd += 256) {
        const int4 a = *(const int4*)&bcnt[(size_t)nd * 8];
        const int4 b = *(const int4*)&bcnt[(size_t)nd * 8 + 4];
        const int d = ((a.x + a.y) + (a.z + a.w)) + ((b.x + b.y) + (b.z + b.w));
        degN[nd] = d;
        dinv[nd] = rsqrtf((float)d + 1.0f);
        sum += d;
    }
    sm[t] = sum;
    __syncthreads();
    for (int off = 128; off > 0; off >>= 1) {
        if (t < off) sm[t] += sm[t + off];
        __syncthreads();
    }
    if (t == 0) partial[blockIdx.x] = sm[0];
}

// B: exclusive scan of 1024 block partials (in place); rowstart[N]=E
__global__ __launch_bounds__(1024) void k_scanB(int* __restrict__ partial,
                                                int* __restrict__ rowstart,
                                                int N, int E) {
    __shared__ int sm[1024];
    const int t = threadIdx.x;
    const int v = partial[t];
    sm[t] = v;
    __syncthreads();
    for (int off = 1; off < 1024; off <<= 1) {
        const int u = (t >= off) ? sm[t - off] : 0;
        __syncthreads();
        sm[t] += u;
        __syncthreads();
    }
    partial[t] = sm[t] - v;   // exclusive
    if (t == 0) rowstart[N] = E;
}

// C: block-local prefix over nodes -> rowstart + per-class claim bases (cur)
__global__ __launch_bounds__(256) void k_scanC(const int* __restrict__ bcnt,
                                               const int* __restrict__ degN,
                                               const int* __restrict__ partial,
                                               int* __restrict__ cur,
                                               int* __restrict__ rowstart,
                                               int N, int npb) {
    __shared__ int sm[256];
    const int t = threadIdx.x;
    const int n0 = blockIdx.x * npb;
    const int n1 = min(n0 + npb, N);
    const int spt = (npb + 255) >> 8;           // contiguous nodes per thread
    const int s = min(n0 + t * spt, n1);
    const int e = min(s + spt, n1);
    int sum = 0;
    for (int nd = s; nd < e; ++nd) sum += degN[nd];
    sm[t] = sum;
    __syncthreads();
    for (int off = 1; off < 256; off <<= 1) {
        const int u = (t >= off) ? sm[t - off] : 0;
        __syncthreads();
        sm[t] += u;
        __syncthreads();
    }
    int run = partial[blockIdx.x] + sm[t] - sum;
    for (int nd = s; nd < e; ++nd) {
        rowstart[nd] = run;
        const int4 a = *(const int4*)&bcnt[(size_t)nd * 8];
        const int4 b = *(const int4*)&bcnt[(size_t)nd * 8 + 4];
        int4 w0, w1;
        w0.x = run;
        w0.y = w0.x + a.x;
        w0.z = w0.y + a.y;
        w0.w = w0.z + a.z;
        w1.x = w0.w + a.w;
        w1.y = w1.x + b.x;
        w1.z = w1.y + b.y;
        w1.w = w1.z + b.z;
        *(int4*)&cur[(size_t)nd * 8] = w0;
        *(int4*)&cur[(size_t)nd * 8 + 4] = w1;
        run = w1.w + b.w;
    }
}

// claim + write col[pos] = src. Same grid/mapping as k_bcnt -> exact capacity.
__global__ void k_bin(const int* __restrict__ src, const int* __restrict__ dst,
                      int* __restrict__ cur, int* __restrict__ col, int E) {
    int i = blockIdx.x * blockDim.x + threadIdx.x;
    const int cls = blockIdx.x & 7;
    const int stride = gridDim.x * blockDim.x;
    for (; i < E; i += stride) {
        const int pos = atomicAdd(&cur[(dst[i] << 3) + cls], 1);
        col[pos] = src[i];
    }
}

// Y[row] = bf16(dinv[row] * (X@W)[row]) ; X is f32 or bf16
template <int K, bool BF16IN>
__global__ __launch_bounds__(256) void k_mm(const void* __restrict__ Xv,
                                            const float* __restrict__ W,
                                            const float* __restrict__ dinv,
                                            unsigned short* __restrict__ Y, int n) {
    __shared__ float WL[K * 64];
    __shared__ float XT[32 * K];
    const int tid = threadIdx.x;
    for (int i = tid * 4; i < K * 64; i += 1024)
        *(float4*)&WL[i] = *(const float4*)&W[i];
    const int rowBase = blockIdx.x * 32;
    const int rows = min(32, n - rowBase);
    if (BF16IN) {
        const unsigned short* xs = (const unsigned short*)Xv + (size_t)rowBase * K;
        for (int i = tid * 4; i < rows * K; i += 1024) {
            const ushort4 u = *(const ushort4*)&xs[i];
            XT[i + 0] = bf2f(u.x); XT[i + 1] = bf2f(u.y);
            XT[i + 2] = bf2f(u.z); XT[i + 3] = bf2f(u.w);
        }
    } else {
        const float* xs = (const float*)Xv + (size_t)rowBase * K;
        for (int i = tid * 4; i < rows * K; i += 1024)
            *(float4*)&XT[i] = *(const float4*)&xs[i];
    }
    __syncthreads();
    const int colf = tid & 63;
    const int rg = tid >> 6;
    float acc[8] = {};
    for (int k4 = 0; k4 < K / 4; ++k4) {
        const float w0 = WL[(k4 * 4 + 0) * 64 + colf];
        const float w1 = WL[(k4 * 4 + 1) * 64 + colf];
        const float w2 = WL[(k4 * 4 + 2) * 64 + colf];
        const float w3 = WL[(k4 * 4 + 3) * 64 + colf];
#pragma unroll
        for (int r = 0; r < 8; ++r) {
            const float4 xv = *(const float4*)&XT[(rg * 8 + r) * K + k4 * 4];
            acc[r] += xv.x * w0 + xv.y * w1 + xv.z * w2 + xv.w * w3;
        }
    }
#pragma unroll
    for (int r = 0; r < 8; ++r) {
        const int row = rowBase + rg * 8 + r;
        if (row < n) Y[(size_t)row * 64 + colf] = f2bf(dinv[row] * acc[r]);
    }
}

// CSR aggregation, one wave per dst node, lane = feature, unroll-8 gathers.
template <bool POOL>
__global__ __launch_bounds__(256) void k_agg(const int* __restrict__ col,
                                             const int* __restrict__ rowstart,
                                             const float* __restrict__ dinv,
                                             const unsigned short* __restrict__ XWs,
                                             const float* __restrict__ bias,
                                             unsigned short* __restrict__ Hout,
                                             const int* __restrict__ batch,
                                             float* __restrict__ emb,
                                             float* __restrict__ cnt, int Nn) {
    const int lane = threadIdx.x & 63;
    const int wid = (blockIdx.x * blockDim.x + threadIdx.x) >> 6;
    const int nw = (gridDim.x * blockDim.x) >> 6;
    const float bl = bias[lane];
    for (int i = wid; i < Nn; i += nw) {
        const int s = rowstart[i], e = rowstart[i + 1];
        float acc = 0.0f;
        int j = s;
        for (; j + 8 <= e; j += 8) {
            const int c0 = col[j + 0], c1 = col[j + 1], c2 = col[j + 2], c3 = col[j + 3];
            const int c4 = col[j + 4], c5 = col[j + 5], c6 = col[j + 6], c7 = col[j + 7];
            const float a0 = bf2f(XWs[(size_t)c0 * 64 + lane]);
            const float a1 = bf2f(XWs[(size_t)c1 * 64 + lane]);
            const float a2 = bf2f(XWs[(size_t)c2 * 64 + lane]);
            const float a3 = bf2f(XWs[(size_t)c3 * 64 + lane]);
            const float a4 = bf2f(XWs[(size_t)c4 * 64 + lane]);
            const float a5 = bf2f(XWs[(size_t)c5 * 64 + lane]);
            const float a6 = bf2f(XWs[(size_t)c6 * 64 + lane]);
            const float a7 = bf2f(XWs[(size_t)c7 * 64 + lane]);
            acc += ((a0 + a1) + (a2 + a3)) + ((a4 + a5) + (a6 + a7));
        }
        for (; j < e; ++j)
            acc += bf2f(XWs[(size_t)col[j] * 64 + lane]);
        const float di = dinv[i];
        const float self = bf2f(XWs[(size_t)i * 64 + lane]);
        const float v = fmaxf(di * (acc + self) + bl, 0.0f);
        if (POOL) {
            const int g = batch[i];
            fatomic(&emb[(size_t)g * 64 + lane], v);
            if (lane == 0) fatomic(&cnt[g], 1.0f);
        } else {
            Hout[(size_t)i * 64 + lane] = f2bf(v);
        }
    }
}

// head: emb -> [e1,e2,|e1-e2|] @ fc1 -> relu -> @ fc2 -> sigmoid
__global__ __launch_bounds__(64) void k_head(const float* __restrict__ emb1, const float* __restrict__ cnt1,
                                             const float* __restrict__ emb2, const float* __restrict__ cnt2,
                                             const float* __restrict__ fc1W, const float* __restrict__ fc1b,
                                             const float* __restrict__ fc2W, const float* __restrict__ fc2b,
                                             float* __restrict__ out) {
    const int g = blockIdx.x;
    const int lane = threadIdx.x;
    __shared__ float comb[192];
    const float c1 = fmaxf(cnt1[g], 1.0f), c2 = fmaxf(cnt2[g], 1.0f);
    const float e1 = emb1[g * 64 + lane] / c1;
    const float e2 = emb2[g * 64 + lane] / c2;
    comb[lane] = e1;
    comb[64 + lane] = e2;
    comb[128 + lane] = fabsf(e1 - e2);
    __syncthreads();
    float acc = fc1b[lane];
    for (int k = 0; k < 192; ++k) acc += comb[k] * fc1W[k * 64 + lane];
    const float o1 = fmaxf(acc, 0.0f);
    float p = o1 * fc2W[lane];
#pragma unroll
    for (int off = 32; off > 0; off >>= 1) p += __shfl_xor(p, off);
    if (lane == 0) out[g] = 1.0f / (1.0f + expf(-(p + fc2b[0])));
}

extern "C" void kernel_launch(void* const* d_in, const int* in_sizes, int n_in,
                              void* d_out, int out_size, void* d_ws, size_t ws_size,
                              hipStream_t stream) {
    const float* x1   = (const float*)d_in[0];
    const int*   ei1  = (const int*)d_in[1];
    const int*   bt1  = (const int*)d_in[2];
    const float* x2   = (const float*)d_in[3];
    const int*   ei2  = (const int*)d_in[4];
    const int*   bt2  = (const int*)d_in[5];
    const float* W1   = (const float*)d_in[6];
    const float* bb1  = (const float*)d_in[7];
    const float* W2   = (const float*)d_in[8];
    const float* bb2  = (const float*)d_in[9];
    const float* fc1W = (const float*)d_in[10];
    const float* fc1b = (const float*)d_in[11];
    const float* fc2W = (const float*)d_in[12];
    const float* fc2b = (const float*)d_in[13];
    float* out = (float*)d_out;

    const int N = in_sizes[0] / 128;
    const int E = in_sizes[1] / 2;
    const int G = out_size;
    const int npb = (N + 1023) / 1024;   // nodes per scan block

    float* dinv   = (float*)d_ws;                    // N
    float* emb1   = dinv + N;                        // G*64
    float* cnt1   = emb1 + (size_t)G * 64;           // G
    float* emb2   = cnt1 + G;                        // G*64
    float* cnt2   = emb2 + (size_t)G * 64;           // G
    int* rowstart = (int*)(cnt2 + G);                // N+1
    int* degN     = rowstart + (N + 1);              // N
    int* partial  = degN + N;                        // 1024
    int* bcnt     = partial + 1024;                  // N*8
    int* cur      = bcnt + (size_t)N * 8;            // N*8
    int* col      = cur + (size_t)N * 8;             // E
    unsigned short* XWs = (unsigned short*)(col + E);      // N*64
    unsigned short* H1  = XWs + (size_t)N * 64;            // N*64

    const int mmGrid = (N + 31) / 32;

    for (int br = 0; br < 2; ++br) {
        const float* X = br ? x2 : x1;
        const int* ei  = br ? ei2 : ei1;
        const int* bt  = br ? bt2 : bt1;
        float* emb = br ? emb2 : emb1;
        float* cnt = br ? cnt2 : cnt1;
        const int* srcp = ei;
        const int* dstp = ei + E;

        hipMemsetAsync(bcnt, 0, (size_t)N * 8 * 4, stream);
        k_bcnt<<<2048, 256, 0, stream>>>(dstp, bcnt, E);
        k_scanA<<<1024, 256, 0, stream>>>(bcnt, degN, dinv, partial, N, npb);
        k_scanB<<<1, 1024, 0, stream>>>(partial, rowstart, N, E);
        k_scanC<<<1024, 256, 0, stream>>>(bcnt, degN, partial, cur, rowstart, N, npb);
        k_bin<<<2048, 256, 0, stream>>>(srcp, dstp, cur, col, E);

        k_mm<128, false><<<mmGrid, 256, 0, stream>>>(X, W1, dinv, XWs, N);
        k_agg<false><<<2048, 256, 0, stream>>>(col, rowstart, dinv, XWs, bb1,
                                               H1, nullptr, nullptr, nullptr, N);
        k_mm<64, true><<<mmGrid, 256, 0, stream>>>(H1, W2, dinv, XWs, N);
        hipMemsetAsync(emb, 0, (size_t)(G * 64 + G) * 4, stream);
        k_agg<true><<<2048, 256, 0, stream>>>(col, rowstart, dinv, XWs, bb2,
                                              nullptr, bt, emb, cnt, N);
    }
    k_head<<<G, 64, 0, stream>>>(emb1, cnt1, emb2, cnt2, fc1W, fc1b, fc2W, fc2b, out);
}